// Round 8
// baseline (313.584 us; speedup 1.0000x reference)
//
#include <hip/hip_runtime.h>
#include <math.h>

// ---------------------------------------------------------------------------
// MS-SSIM + MSE loss, (16,3,512,512) f32, 5 pyramid levels.
// R8: LDS-free streaming for W>=128. Each lane owns one output column and
// streams 42 rows. The 11-col H-window comes from 3 overlapping dwordx4
// global loads per image (offsets 0/16/28 B) -> L1 serves the redundancy.
// No ds ops, no fences: pure load->fma dataflow, compiler pipelines freely.
// V-pass = register-renamed transposed FIR (unroll 11). Last col-strip is
// shifted left 10 cols so windows never go OOB; its ownership value for
// MSE/avgpool is window[10] (static index), and only lanes>=10 emit SSIM.
// W=64/32 use the proven R7 LDS-ring kernel (tiny cost). No atomics.
// ---------------------------------------------------------------------------

#define NPLANES 48

struct GaussW { float g[11]; };

typedef float f4u __attribute__((ext_vector_type(4), aligned(4)));

// ws float offsets: pyramids + per-WAVE partial areas
#define PYR2_OFF  4177920
#define P_L0      8355840   // 6144 pairs
#define P_L1      8368128   // 1536 pairs
#define P_L2      8371200   // 384 pairs
#define P_L3      8371968   // 96 pairs
#define P_L4      8372160   // 48 pairs
#define P_MSE     8372256   // 6144 singles

#define C1F 1.0e-4f
#define C2F 9.0e-4f

// ---------------------------------------------------------------------------
template <int LOGW, int DO_MSE, int DO_POOL>
__global__ __launch_bounds__(256, 4) void ssim_nolds(
    const float* __restrict__ x1, const float* __restrict__ x2, GaussW gw,
    float* __restrict__ partials, float* __restrict__ msep,
    float* __restrict__ d1, float* __restrict__ d2)
{
  constexpr int W = 1 << LOGW;
  constexpr int Ho = W - 10;
  constexpr int CS = W >> 6;          // 64-col strips (last shifted left 10)
  constexpr int RS = (Ho + 31) >> 5;  // 32-row strips
  constexpr int PW = RS * CS;
  constexpr int W2 = W >> 1;

  const int tid = threadIdx.x;
  const int wid = tid >> 6, lane = tid & 63;
  const int gwid = blockIdx.x * 4 + wid;
  const int plane = gwid / PW;
  const int rem = gwid - plane * PW;
  const int rsi = rem / CS;
  const int csi = rem - rsi * CS;
  const bool lastc = (csi == CS - 1);

  const int gr0 = 32 * rsi;
  const int c0 = lastc ? (W - 74) : (64 * csi);
  const int gc = c0 + lane;
  int ROWS = W - gr0; if (ROWS > 42) ROWS = 42;   // = min(42, Ho-gr0+10)
  const bool emit_ok = (!lastc) || (lane >= 10);

  const size_t pb = (size_t)plane * W * W;
  const float* q1 = x1 + pb + (size_t)gr0 * W + gc;
  const float* q2 = x2 + pb + (size_t)gr0 * W + gc;

  float mse_acc = 0.f, ssim_acc = 0.f, cs_acc = 0.f;
  float ppa = 0.f, ppb = 0.f;  // prev-row ownership values (pool)

  // transposed-FIR accumulators: acc*[10] emits out row (rr-10)
  float acc0[11], acc1[11], acc2[11], acc3[11], acc4[11];
#pragma unroll
  for (int j = 0; j < 11; ++j) {
    acc0[j] = 0.f; acc1[j] = 0.f; acc2[j] = 0.f; acc3[j] = 0.f; acc4[j] = 0.f;
  }

  int roff = 0;
#pragma unroll 1
  for (int t = 0; t < 4; ++t) {
#pragma unroll
    for (int u = 0; u < 11; ++u) {
      const int rr = 11 * t + u;     // row index; u == rr % 11 (static)
      if (rr < ROWS) {
        // ---- 11-col windows, 3 overlapping dwordx4 per image ----
        const float* p1 = q1 + roff;
        const float* p2 = q2 + roff;
        f4u xa = *(const f4u*)(p1);
        f4u xb = *(const f4u*)(p1 + 4);
        f4u xc = *(const f4u*)(p1 + 7);   // cols gc+7..gc+10
        f4u za = *(const f4u*)(p2);
        f4u zb = *(const f4u*)(p2 + 4);
        f4u zc = *(const f4u*)(p2 + 7);
        roff += W;

        float A[11], B[11];
        A[0]=xa.x; A[1]=xa.y; A[2]=xa.z; A[3]=xa.w;
        A[4]=xb.x; A[5]=xb.y; A[6]=xb.z; A[7]=xb.w;
        A[8]=xc.y; A[9]=xc.z; A[10]=xc.w;
        B[0]=za.x; B[1]=za.y; B[2]=za.z; B[3]=za.w;
        B[4]=zb.x; B[5]=zb.y; B[6]=zb.z; B[7]=zb.w;
        B[8]=zc.y; B[9]=zc.z; B[10]=zc.w;

        // ownership value (MSE / pool): own col, or col+10 on last strip
        float pa = lastc ? A[10] : A[0];
        float pbv = lastc ? B[10] : B[0];

        if (DO_MSE && rr < 32) {
          float d_ = pa - pbv;
          mse_acc = fmaf(d_, d_, mse_acc);
        }

        // ---- H-pass: 7 ops/tap, 5 fields ----
        float s1 = 0.f, s2 = 0.f, s11 = 0.f, s22 = 0.f, s12 = 0.f;
#pragma unroll
        for (int k = 0; k < 11; ++k) {
          float av = A[k], bv = B[k], w = gw.g[k];
          float wa = w * av, wb = w * bv;
          s1 += wa; s2 += wb;
          s11 = fmaf(wa, av, s11);
          s22 = fmaf(wb, bv, s22);
          s12 = fmaf(wa, bv, s12);
        }

        // ---- V-pass: shift-accumulate (renamed over the 11-unroll) ----
#pragma unroll
        for (int j = 10; j >= 1; --j) {
          acc0[j] = fmaf(gw.g[j], s1, acc0[j - 1]);
          acc1[j] = fmaf(gw.g[j], s2, acc1[j - 1]);
          acc2[j] = fmaf(gw.g[j], s11, acc2[j - 1]);
          acc3[j] = fmaf(gw.g[j], s22, acc3[j - 1]);
          acc4[j] = fmaf(gw.g[j], s12, acc4[j - 1]);
        }
        acc0[0] = gw.g[0] * s1;
        acc1[0] = gw.g[0] * s2;
        acc2[0] = gw.g[0] * s11;
        acc3[0] = gw.g[0] * s22;
        acc4[0] = gw.g[0] * s12;

        // ---- emit SSIM/CS for out row (gr0 + rr - 10) ----
        if (rr >= 10 && emit_ok) {
          float m1 = acc0[10], m2 = acc1[10];
          float m1sq = m1 * m1, m2sq = m2 * m2, m12 = m1 * m2;
          float v1 = 2.f * (acc4[10] - m12) + C2F;
          float v2 = (acc2[10] - m1sq) + (acc3[10] - m2sq) + C2F;
          float csv = v1 * __builtin_amdgcn_rcpf(v2);
          cs_acc += csv;
          ssim_acc += csv * (2.f * m12 + C1F) *
                      __builtin_amdgcn_rcpf(m1sq + m2sq + C1F);
        }

        // ---- fused 2x2 avgpool on ownership cols, rows (rr-1, rr) ----
        if (DO_POOL && (rr & 1) && rr < 32) {
          float sa = pa + ppa;
          float sb = pbv + ppb;
          float na = sa + __shfl_xor(sa, 1);
          float nb = sb + __shfl_xor(sb, 1);
          if ((lane & 1) == 0) {
            int orow = 16 * rsi + (rr >> 1);
            int ocol = (lastc ? (W2 - 32) : (32 * csi)) + (lane >> 1);
            size_t ob = (size_t)plane * W2 * W2 + (size_t)orow * W2 + ocol;
            d1[ob] = 0.25f * na;
            d2[ob] = 0.25f * nb;
          }
        }
        ppa = pa; ppb = pbv;
      }
    }
  }

  // ---- wave reduce + per-wave partial write ----
#pragma unroll
  for (int off = 32; off; off >>= 1) {
    ssim_acc += __shfl_down(ssim_acc, off);
    cs_acc += __shfl_down(cs_acc, off);
    if (DO_MSE) mse_acc += __shfl_down(mse_acc, off);
  }
  if (lane == 0) {
    partials[2 * gwid] = ssim_acc;
    partials[2 * gwid + 1] = cs_acc;
    if (DO_MSE) msep[gwid] = mse_acc;
  }
}

// ---------------------------------------------------------------------------
// R7 LDS-ring kernel, kept for the tiny W=64 / W=32 levels.
template <int LOGW, int DO_POOL>
__global__ __launch_bounds__(256, 4) void ssim_small(
    const float* __restrict__ x1, const float* __restrict__ x2, GaussW gw,
    float* __restrict__ partials, float* __restrict__ d1, float* __restrict__ d2)
{
  constexpr int W = 1 << LOGW;
  constexpr int Ho = W - 10;
  constexpr int CS = (Ho + 63) >> 6;
  constexpr int RS = (Ho + 31) >> 5;
  constexpr int PW = RS * CS;
  constexpr int W2 = W >> 1;

  __shared__ float rowbuf[4][11][2][76];

  const int tid = threadIdx.x;
  const int wid = tid >> 6, lane = tid & 63;
  const int gwid = blockIdx.x * 4 + wid;
  const int plane = gwid / PW;
  const int rem = gwid - plane * PW;
  const int rsi = rem / CS;
  const int csi = rem - rsi * CS;

  const int gr0 = 32 * rsi;
  const int c0 = 64 * csi;
  const int gc = c0 + lane;
  int ROWS = Ho - gr0 + 10; if (ROWS > 42) ROWS = 42;

  const size_t pb = (size_t)plane * W * W;
  const float* q1 = x1 + pb + gc;
  const float* q2 = x2 + pb + gc;
  const bool cok = gc < W;
  const bool eok = (lane < 10) && (gc + 64 < W);

  float (*rb)[2][76] = rowbuf[wid];
  float ssim_acc = 0.f, cs_acc = 0.f;

  float acc0[11], acc1[11], acc2[11], acc3[11], acc4[11];
#pragma unroll
  for (int j = 0; j < 11; ++j) {
    acc0[j] = 0.f; acc1[j] = 0.f; acc2[j] = 0.f; acc3[j] = 0.f; acc4[j] = 0.f;
  }

#define LOADROW(R, V)                                                   \
  {                                                                     \
    V.x = 0.f; V.y = 0.f; V.z = 0.f; V.w = 0.f;                         \
    if ((R) < ROWS) {                                                   \
      size_t ro = (size_t)(gr0 + (R)) * W;                              \
      if (cok) { V.x = q1[ro]; V.y = q2[ro]; }                          \
      if (eok) { V.z = q1[ro + 64]; V.w = q2[ro + 64]; }                \
    }                                                                   \
  }
#define WRITEROW(SLOT, V)                                               \
  {                                                                     \
    rb[SLOT][0][lane] = V.x;                                            \
    rb[SLOT][1][lane] = V.y;                                            \
    if (lane < 10) {                                                    \
      rb[SLOT][0][64 + lane] = V.z;                                     \
      rb[SLOT][1][64 + lane] = V.w;                                     \
    }                                                                   \
  }

  float4 vA, vB, vT;
  LOADROW(0, vT)
  WRITEROW(0, vT)
  LOADROW(1, vA)
  LOADROW(2, vB)

  for (int t = 0; t < 4; ++t) {
#pragma unroll
    for (int u = 0; u < 11; ++u) {
      const int rr = 11 * t + u;
      const int sW = (u + 1) % 11;
      const int sP = (u + 10) % 11;

      asm volatile("s_waitcnt lgkmcnt(0)" ::: "memory");
      __builtin_amdgcn_sched_barrier(0);

      if (rr + 1 < ROWS) WRITEROW(sW, vA)
      vA = vB;
      LOADROW(rr + 3, vB)

      const float* r1 = &rb[u][0][lane];
      const float* r2 = &rb[u][1][lane];
      float s1 = 0.f, s2 = 0.f, s11 = 0.f, s22 = 0.f, s12 = 0.f;
#pragma unroll
      for (int k = 0; k < 11; ++k) {
        float av = r1[k], bv = r2[k], w = gw.g[k];
        float wa = w * av, wb = w * bv;
        s1 += wa; s2 += wb;
        s11 = fmaf(wa, av, s11);
        s22 = fmaf(wb, bv, s22);
        s12 = fmaf(wa, bv, s12);
      }

#pragma unroll
      for (int j = 10; j >= 1; --j) {
        acc0[j] = fmaf(gw.g[j], s1, acc0[j - 1]);
        acc1[j] = fmaf(gw.g[j], s2, acc1[j - 1]);
        acc2[j] = fmaf(gw.g[j], s11, acc2[j - 1]);
        acc3[j] = fmaf(gw.g[j], s22, acc3[j - 1]);
        acc4[j] = fmaf(gw.g[j], s12, acc4[j - 1]);
      }
      acc0[0] = gw.g[0] * s1;
      acc1[0] = gw.g[0] * s2;
      acc2[0] = gw.g[0] * s11;
      acc3[0] = gw.g[0] * s22;
      acc4[0] = gw.g[0] * s12;

      if (rr >= 10 && rr < ROWS && gc < Ho) {
        float m1 = acc0[10], m2 = acc1[10];
        float m1sq = m1 * m1, m2sq = m2 * m2, m12 = m1 * m2;
        float v1 = 2.f * (acc4[10] - m12) + C2F;
        float v2 = (acc2[10] - m1sq) + (acc3[10] - m2sq) + C2F;
        float csv = v1 * __builtin_amdgcn_rcpf(v2);
        cs_acc += csv;
        ssim_acc += csv * (2.f * m12 + C1F) *
                    __builtin_amdgcn_rcpf(m1sq + m2sq + C1F);
      }

      if (DO_POOL && (rr & 1) && rr < 32 && rr < ROWS && lane < 32) {
        float a00 = rb[sP][0][2 * lane], a01 = rb[sP][0][2 * lane + 1];
        float a10 = rb[u][0][2 * lane],  a11 = rb[u][0][2 * lane + 1];
        float b00 = rb[sP][1][2 * lane], b01 = rb[sP][1][2 * lane + 1];
        float b10 = rb[u][1][2 * lane],  b11 = rb[u][1][2 * lane + 1];
        int orow = 16 * rsi + (rr >> 1);
        size_t ob = (size_t)plane * W2 * W2 + (size_t)orow * W2 + (c0 >> 1) + lane;
        d1[ob] = 0.25f * ((a00 + a01) + (a10 + a11));
        d2[ob] = 0.25f * ((b00 + b01) + (b10 + b11));
      }
    }
  }
#undef LOADROW
#undef WRITEROW

#pragma unroll
  for (int off = 32; off; off >>= 1) {
    ssim_acc += __shfl_down(ssim_acc, off);
    cs_acc += __shfl_down(cs_acc, off);
  }
  if (lane == 0) {
    partials[2 * gwid] = ssim_acc;
    partials[2 * gwid + 1] = cs_acc;
  }
}

// ---------------------------------------------------------------------------
__global__ __launch_bounds__(256) void final_kernel(
    const float* __restrict__ ws, float* __restrict__ out)
{
  __shared__ double sred[2][4];
  __shared__ double fin[11];  // ssim[5], cs[5], mse
  const int tid = threadIdx.x;
  const int offs[5] = {P_L0, P_L1, P_L2, P_L3, P_L4};
  const int cnts[5] = {6144, 1536, 384, 96, 48};

  for (int l = 0; l < 5; ++l) {
    double s0 = 0.0, s1 = 0.0;
    for (int i = tid; i < cnts[l]; i += 256) {
      s0 += (double)ws[offs[l] + 2 * i];
      s1 += (double)ws[offs[l] + 2 * i + 1];
    }
#pragma unroll
    for (int off = 32; off; off >>= 1) {
      s0 += __shfl_down(s0, off);
      s1 += __shfl_down(s1, off);
    }
    if ((tid & 63) == 0) { sred[0][tid >> 6] = s0; sred[1][tid >> 6] = s1; }
    __syncthreads();
    if (tid == 0) {
      double aa = 0.0, bb = 0.0;
      for (int i = 0; i < 4; ++i) { aa += sred[0][i]; bb += sred[1][i]; }
      fin[l] = aa;
      fin[5 + l] = bb;
    }
    __syncthreads();
  }

  {
    double s0 = 0.0;
    for (int i = tid; i < 6144; i += 256) s0 += (double)ws[P_MSE + i];
#pragma unroll
    for (int off = 32; off; off >>= 1) s0 += __shfl_down(s0, off);
    if ((tid & 63) == 0) sred[0][tid >> 6] = s0;
    __syncthreads();
    if (tid == 0) {
      double aa = 0.0;
      for (int i = 0; i < 4; ++i) aa += sred[0][i];
      fin[10] = aa;
    }
    __syncthreads();
  }

  if (tid == 0) {
    const double wts[5] = {0.0448, 0.2856, 0.3001, 0.2363, 0.1333};
    const double dims[5] = {502.0, 246.0, 118.0, 54.0, 22.0};
    double mssim[5], mcs[5];
    for (int l = 0; l < 5; ++l) {
      double n = 48.0 * dims[l] * dims[l];
      mssim[l] = fin[l] / n;
      mcs[l] = fin[5 + l] / n;
    }
    // literal pytorch_msssim translation: prod(pow1[:-1] * pow2[-1])
    double p2last = pow(mssim[4], wts[4]);
    double prod = 1.0;
    for (int i = 0; i < 4; ++i) prod *= pow(mcs[i], wts[i]) * p2last;
    double msssim = prod;
    double mse = fin[10] / 12582912.0;
    out[0] = (float)(mse - msssim + 1.0);
    out[1] = (float)msssim;
  }
}

// ---------------------------------------------------------------------------
extern "C" void kernel_launch(void* const* d_in, const int* in_sizes, int n_in,
                              void* d_out, int out_size, void* d_ws, size_t ws_size,
                              hipStream_t stream)
{
  const float* rec = (const float*)d_in[0];   // reconst
  const float* orig = (const float*)d_in[1];  // original
  float* ws = (float*)d_ws;
  float* out = (float*)d_out;

  GaussW gw;
  {
    double g[11], s = 0.0;
    for (int i = 0; i < 11; ++i) {
      double x = (double)i - 5.0;
      g[i] = exp(-(x * x) / 4.5);
      s += g[i];
    }
    for (int i = 0; i < 11; ++i) gw.g[i] = (float)(g[i] / s);
  }

  // pyramid pointers
  float* A1 = ws + 0;
  float* A2 = ws + 3145728;
  float* A3 = ws + 3932160;
  float* A4 = ws + 4128768;
  float* B1 = ws + PYR2_OFF;
  float* B2 = ws + PYR2_OFF + 3145728;
  float* B3 = ws + PYR2_OFF + 3932160;
  float* B4 = ws + PYR2_OFF + 4128768;

  // L0..L2: LDS-free streaming kernels
  ssim_nolds<9, 1, 1><<<dim3(1536), 256, 0, stream>>>(
      orig, rec, gw, ws + P_L0, ws + P_MSE, A1, B1);     // 16x8 strips
  ssim_nolds<8, 0, 1><<<dim3(384), 256, 0, stream>>>(
      A1, B1, gw, ws + P_L1, nullptr, A2, B2);           // 8x4
  ssim_nolds<7, 0, 1><<<dim3(96), 256, 0, stream>>>(
      A2, B2, gw, ws + P_L2, nullptr, A3, B3);           // 4x2
  // L3/L4: LDS-ring kernel (W < 74 needs halo staging)
  ssim_small<6, 1><<<dim3(24), 256, 0, stream>>>(
      A3, B3, gw, ws + P_L3, A4, B4);                    // 2x1
  ssim_small<5, 0><<<dim3(12), 256, 0, stream>>>(
      A4, B4, gw, ws + P_L4, nullptr, nullptr);          // 1x1

  final_kernel<<<dim3(1), dim3(256), 0, stream>>>(ws, out);
}

// Round 9
// 236.935 us; speedup vs baseline: 1.3235x; 1.3235x over previous
//
#include <hip/hip_runtime.h>
#include <math.h>

// ---------------------------------------------------------------------------
// MS-SSIM + MSE loss, (16,3,512,512) f32, 5 pyramid levels.
// R9: packed-f32 column streaming. Each lane owns TWO output columns (v2f);
// wave covers 128 raw cols + 10 halo staged in a wave-private 11-slot LDS
// ring (slot indices static via unroll-11). Per row: 6 v2f LDS reads/img
// (ds_read2_b64-mergeable) -> packed H-pass (77 pk-ops) -> packed
// register-renamed transposed FIR (60 pk-ops) -> packed SSIM/CS with a
// divergence-free post-mask. No explicit fences (compiler lgkmcnt handles
// LDS deps). MSE/avgpool ride the load pipeline (own cols only, no LDS).
// W=64/32 use the R7 scalar LDS-ring kernel. No atomics.
// ---------------------------------------------------------------------------

#define NPLANES 48

struct GaussW { float g[11]; };

typedef float v2f __attribute__((ext_vector_type(2)));

// ws float offsets: pyramids + per-WAVE partial areas
#define PYR2_OFF  4177920
#define P_L0      8355840   // 3072 pairs
#define P_L1      8361984   // 768 pairs
#define P_L2      8363520   // 192 pairs
#define P_L3      8363904   // 96 pairs
#define P_L4      8364096   // 48 pairs
#define P_MSE     8364192   // 3072 singles

#define C1F 1.0e-4f
#define C2F 9.0e-4f

// window pair {w[k], w[k+1]} from v2f-packed window r[] (k static)
__device__ __forceinline__ v2f wpair(const v2f* r, int k) {
  if ((k & 1) == 0) return r[k >> 1];
  return __builtin_shufflevector(r[k >> 1], r[(k >> 1) + 1], 1, 2);
}

// ---------------------------------------------------------------------------
template <int LOGW, int DO_MSE, int DO_POOL>
__global__ __launch_bounds__(256, 3) void ssim_pk(
    const float* __restrict__ x1, const float* __restrict__ x2, GaussW gw,
    float* __restrict__ partials, float* __restrict__ msep,
    float* __restrict__ d1, float* __restrict__ d2)
{
  constexpr int W = 1 << LOGW;
  constexpr int Ho = W - 10;
  constexpr int CS = (Ho + 127) >> 7;  // 128-raw-col strips
  constexpr int RS = (Ho + 31) >> 5;   // 32-out-row bands
  constexpr int PW = RS * CS;
  constexpr int W2 = W >> 1;

  // [wave][slot][img][b64 col-slot]; 140 raw cols as 70 v2f. 49280 B total.
  __shared__ v2f buf[4][11][2][70];

  const int tid = threadIdx.x;
  const int wid = tid >> 6, lane = tid & 63;
  const int gwid = blockIdx.x * 4 + wid;
  const int plane = gwid / PW;
  const int rem = gwid - plane * PW;
  const int rsi = rem / CS;
  const int csi = rem - rsi * CS;

  const int gr0 = 32 * rsi;
  const int c0 = 128 * csi;
  const int cb = c0 + 2 * lane;        // lane's first raw col
  int ROWS = W - gr0; if (ROWS > 42) ROWS = 42;
  const bool hok = (lane < 5) && (c0 + 138 <= W);  // halo cols exist
  const bool hwr = (lane < 5);

  const size_t pb = (size_t)plane * W * W;
  const float* q1 = x1 + pb + (size_t)gr0 * W + cb;
  const float* q2 = x2 + pb + (size_t)gr0 * W + cb;

  v2f (*rbw)[2][70] = buf[wid];

  v2f mse_acc = {0.f, 0.f}, ssim_acc = {0.f, 0.f}, cs_acc = {0.f, 0.f};
  v2f ppa = {0.f, 0.f}, ppb = {0.f, 0.f};

  // packed transposed-FIR accumulators: acc*[10] emits out row (rr-10)
  v2f acc0[11], acc1[11], acc2[11], acc3[11], acc4[11];
#pragma unroll
  for (int j = 0; j < 11; ++j) {
    acc0[j] = (v2f){0.f, 0.f}; acc1[j] = (v2f){0.f, 0.f};
    acc2[j] = (v2f){0.f, 0.f}; acc3[j] = (v2f){0.f, 0.f};
    acc4[j] = (v2f){0.f, 0.f};
  }

#define LOADROW(R, A, B, AH, BH)                                        \
  {                                                                     \
    A = (v2f){0.f, 0.f}; B = (v2f){0.f, 0.f};                           \
    AH = (v2f){0.f, 0.f}; BH = (v2f){0.f, 0.f};                         \
    if ((R) < ROWS) {                                                   \
      size_t ro = (size_t)(R) * W;                                      \
      A = *(const v2f*)(q1 + ro);                                       \
      B = *(const v2f*)(q2 + ro);                                       \
      if (hok) {                                                        \
        AH = *(const v2f*)(q1 + ro + 128);                              \
        BH = *(const v2f*)(q2 + ro + 128);                              \
      }                                                                 \
      if (DO_MSE && (R) < 32) {                                         \
        v2f d_ = A - B;                                                 \
        mse_acc = __builtin_elementwise_fma(d_, d_, mse_acc);           \
      }                                                                 \
    }                                                                   \
  }

#define WRITEROW(SLOT, A, B, AH, BH)                                    \
  {                                                                     \
    rbw[SLOT][0][lane] = A;                                             \
    rbw[SLOT][1][lane] = B;                                             \
    if (hwr) {                                                          \
      rbw[SLOT][0][64 + lane] = AH;                                     \
      rbw[SLOT][1][64 + lane] = BH;                                     \
    }                                                                   \
  }

  // prologue: row 0 staged in slot 0
  v2f a0, b0, ah0, bh0;
  LOADROW(0, a0, b0, ah0, bh0)
  WRITEROW(0, a0, b0, ah0, bh0)
  ppa = a0; ppb = b0;

#pragma unroll 1
  for (int t = 0; t < 4; ++t) {
#pragma unroll
    for (int u = 0; u < 11; ++u) {
      const int rr = 11 * t + u;       // row in slot u (u == rr % 11)
      if (rr < ROWS) {
        const int sW = (u + 1) % 11;   // slot for row rr+1 (static)

        // load + stage row rr+1; pool on own cols rides the load pipe
        v2f a, b, ah, bh;
        const int R = rr + 1;
        LOADROW(R, a, b, ah, bh)
        if (R < ROWS) {
          WRITEROW(sW, a, b, ah, bh)
          if (DO_POOL && (R & 1) && R < 32) {
            int orow = 16 * rsi + (R >> 1);
            size_t ob = (size_t)plane * W2 * W2 + (size_t)orow * W2 +
                        (c0 >> 1) + lane;
            d1[ob] = 0.25f * ((ppa.x + ppa.y) + (a.x + a.y));
            d2[ob] = 0.25f * ((ppb.x + ppb.y) + (b.x + b.y));
          }
          ppa = a; ppb = b;
        }

        // ---- read 12-col windows (6 v2f per image, consecutive slots) ----
        v2f w1[6], w2[6];
        {
          const v2f* r1 = &rbw[u][0][lane];
          const v2f* r2 = &rbw[u][1][lane];
#pragma unroll
          for (int i = 0; i < 6; ++i) { w1[i] = r1[i]; w2[i] = r2[i]; }
        }

        // ---- packed H-pass: 5 fields, 11 taps, 2 px ----
        v2f s1 = {0.f, 0.f}, s2 = {0.f, 0.f};
        v2f s11 = {0.f, 0.f}, s22 = {0.f, 0.f}, s12 = {0.f, 0.f};
#pragma unroll
        for (int k = 0; k < 11; ++k) {
          v2f av = wpair(w1, k), bv = wpair(w2, k);
          v2f wk = {gw.g[k], gw.g[k]};
          v2f wa = wk * av, wb = wk * bv;
          s1 += wa; s2 += wb;
          s11 = __builtin_elementwise_fma(wa, av, s11);
          s22 = __builtin_elementwise_fma(wb, bv, s22);
          s12 = __builtin_elementwise_fma(wa, bv, s12);
        }

        // ---- packed V-pass: shift-accumulate (renamed over unroll-11) ----
#pragma unroll
        for (int j = 10; j >= 1; --j) {
          v2f gj = {gw.g[j], gw.g[j]};
          acc0[j] = __builtin_elementwise_fma(gj, s1, acc0[j - 1]);
          acc1[j] = __builtin_elementwise_fma(gj, s2, acc1[j - 1]);
          acc2[j] = __builtin_elementwise_fma(gj, s11, acc2[j - 1]);
          acc3[j] = __builtin_elementwise_fma(gj, s22, acc3[j - 1]);
          acc4[j] = __builtin_elementwise_fma(gj, s12, acc4[j - 1]);
        }
        {
          v2f g0 = {gw.g[0], gw.g[0]};
          acc0[0] = g0 * s1;  acc1[0] = g0 * s2;
          acc2[0] = g0 * s11; acc3[0] = g0 * s22; acc4[0] = g0 * s12;
        }

        // ---- packed SSIM/CS emit (no divergence; post-masked) ----
        if (rr >= 10) {
          const v2f two = {2.f, 2.f}, c1v = {C1F, C1F}, c2v = {C2F, C2F};
          v2f m1 = acc0[10], m2 = acc1[10];
          v2f m1sq = m1 * m1, m2sq = m2 * m2, m12 = m1 * m2;
          v2f v1 = __builtin_elementwise_fma(two, acc4[10] - m12, c2v);
          v2f v2v = (acc2[10] - m1sq) + (acc3[10] - m2sq) + c2v;
          v2f rc2 = {__builtin_amdgcn_rcpf(v2v.x),
                     __builtin_amdgcn_rcpf(v2v.y)};
          v2f csv = v1 * rc2;
          cs_acc += csv;
          v2f num = __builtin_elementwise_fma(two, m12, c1v);
          v2f den = m1sq + m2sq + c1v;
          v2f rc1 = {__builtin_amdgcn_rcpf(den.x),
                     __builtin_amdgcn_rcpf(den.y)};
          ssim_acc += csv * num * rc1;
        }
      }
    }
  }
#undef LOADROW
#undef WRITEROW

  // column-validity mask (same every row): zero out px with col >= Ho
  {
    v2f mk = {(cb < Ho) ? 1.f : 0.f, (cb + 1 < Ho) ? 1.f : 0.f};
    ssim_acc *= mk;
    cs_acc *= mk;
  }

  // ---- wave reduce (per component) + per-wave partial write ----
  float sa = ssim_acc.x + ssim_acc.y;
  float ca = cs_acc.x + cs_acc.y;
  float ma = DO_MSE ? (mse_acc.x + mse_acc.y) : 0.f;
#pragma unroll
  for (int off = 32; off; off >>= 1) {
    sa += __shfl_down(sa, off);
    ca += __shfl_down(ca, off);
    if (DO_MSE) ma += __shfl_down(ma, off);
  }
  if (lane == 0) {
    partials[2 * gwid] = sa;
    partials[2 * gwid + 1] = ca;
    if (DO_MSE) msep[gwid] = ma;
  }
}

// ---------------------------------------------------------------------------
// R7 scalar LDS-ring kernel, kept for the tiny W=64 / W=32 levels.
template <int LOGW, int DO_POOL>
__global__ __launch_bounds__(256, 4) void ssim_small(
    const float* __restrict__ x1, const float* __restrict__ x2, GaussW gw,
    float* __restrict__ partials, float* __restrict__ d1, float* __restrict__ d2)
{
  constexpr int W = 1 << LOGW;
  constexpr int Ho = W - 10;
  constexpr int CS = (Ho + 63) >> 6;
  constexpr int RS = (Ho + 31) >> 5;
  constexpr int PW = RS * CS;
  constexpr int W2 = W >> 1;

  __shared__ float rowbuf[4][11][2][76];

  const int tid = threadIdx.x;
  const int wid = tid >> 6, lane = tid & 63;
  const int gwid = blockIdx.x * 4 + wid;
  const int plane = gwid / PW;
  const int rem = gwid - plane * PW;
  const int rsi = rem / CS;
  const int csi = rem - rsi * CS;

  const int gr0 = 32 * rsi;
  const int c0 = 64 * csi;
  const int gc = c0 + lane;
  int ROWS = Ho - gr0 + 10; if (ROWS > 42) ROWS = 42;

  const size_t pb = (size_t)plane * W * W;
  const float* q1 = x1 + pb + gc;
  const float* q2 = x2 + pb + gc;
  const bool cok = gc < W;
  const bool eok = (lane < 10) && (gc + 64 < W);

  float (*rb)[2][76] = rowbuf[wid];
  float ssim_acc = 0.f, cs_acc = 0.f;

  float acc0[11], acc1[11], acc2[11], acc3[11], acc4[11];
#pragma unroll
  for (int j = 0; j < 11; ++j) {
    acc0[j] = 0.f; acc1[j] = 0.f; acc2[j] = 0.f; acc3[j] = 0.f; acc4[j] = 0.f;
  }

#define LOADROW(R, V)                                                   \
  {                                                                     \
    V.x = 0.f; V.y = 0.f; V.z = 0.f; V.w = 0.f;                         \
    if ((R) < ROWS) {                                                   \
      size_t ro = (size_t)(gr0 + (R)) * W;                              \
      if (cok) { V.x = q1[ro]; V.y = q2[ro]; }                          \
      if (eok) { V.z = q1[ro + 64]; V.w = q2[ro + 64]; }                \
    }                                                                   \
  }
#define WRITEROW(SLOT, V)                                               \
  {                                                                     \
    rb[SLOT][0][lane] = V.x;                                            \
    rb[SLOT][1][lane] = V.y;                                            \
    if (lane < 10) {                                                    \
      rb[SLOT][0][64 + lane] = V.z;                                     \
      rb[SLOT][1][64 + lane] = V.w;                                     \
    }                                                                   \
  }

  float4 vA, vB, vT;
  LOADROW(0, vT)
  WRITEROW(0, vT)
  LOADROW(1, vA)
  LOADROW(2, vB)

  for (int t = 0; t < 4; ++t) {
#pragma unroll
    for (int u = 0; u < 11; ++u) {
      const int rr = 11 * t + u;
      const int sW = (u + 1) % 11;
      const int sP = (u + 10) % 11;

      asm volatile("s_waitcnt lgkmcnt(0)" ::: "memory");
      __builtin_amdgcn_sched_barrier(0);

      if (rr + 1 < ROWS) WRITEROW(sW, vA)
      vA = vB;
      LOADROW(rr + 3, vB)

      const float* r1 = &rb[u][0][lane];
      const float* r2 = &rb[u][1][lane];
      float s1 = 0.f, s2 = 0.f, s11 = 0.f, s22 = 0.f, s12 = 0.f;
#pragma unroll
      for (int k = 0; k < 11; ++k) {
        float av = r1[k], bv = r2[k], w = gw.g[k];
        float wa = w * av, wb = w * bv;
        s1 += wa; s2 += wb;
        s11 = fmaf(wa, av, s11);
        s22 = fmaf(wb, bv, s22);
        s12 = fmaf(wa, bv, s12);
      }

#pragma unroll
      for (int j = 10; j >= 1; --j) {
        acc0[j] = fmaf(gw.g[j], s1, acc0[j - 1]);
        acc1[j] = fmaf(gw.g[j], s2, acc1[j - 1]);
        acc2[j] = fmaf(gw.g[j], s11, acc2[j - 1]);
        acc3[j] = fmaf(gw.g[j], s22, acc3[j - 1]);
        acc4[j] = fmaf(gw.g[j], s12, acc4[j - 1]);
      }
      acc0[0] = gw.g[0] * s1;
      acc1[0] = gw.g[0] * s2;
      acc2[0] = gw.g[0] * s11;
      acc3[0] = gw.g[0] * s22;
      acc4[0] = gw.g[0] * s12;

      if (rr >= 10 && rr < ROWS && gc < Ho) {
        float m1 = acc0[10], m2 = acc1[10];
        float m1sq = m1 * m1, m2sq = m2 * m2, m12 = m1 * m2;
        float v1 = 2.f * (acc4[10] - m12) + C2F;
        float v2 = (acc2[10] - m1sq) + (acc3[10] - m2sq) + C2F;
        float csv = v1 * __builtin_amdgcn_rcpf(v2);
        cs_acc += csv;
        ssim_acc += csv * (2.f * m12 + C1F) *
                    __builtin_amdgcn_rcpf(m1sq + m2sq + C1F);
      }

      if (DO_POOL && (rr & 1) && rr < 32 && rr < ROWS && lane < 32) {
        float a00 = rb[sP][0][2 * lane], a01 = rb[sP][0][2 * lane + 1];
        float a10 = rb[u][0][2 * lane],  a11 = rb[u][0][2 * lane + 1];
        float b00 = rb[sP][1][2 * lane], b01 = rb[sP][1][2 * lane + 1];
        float b10 = rb[u][1][2 * lane],  b11 = rb[u][1][2 * lane + 1];
        int orow = 16 * rsi + (rr >> 1);
        size_t ob = (size_t)plane * W2 * W2 + (size_t)orow * W2 + (c0 >> 1) + lane;
        d1[ob] = 0.25f * ((a00 + a01) + (a10 + a11));
        d2[ob] = 0.25f * ((b00 + b01) + (b10 + b11));
      }
    }
  }
#undef LOADROW
#undef WRITEROW

#pragma unroll
  for (int off = 32; off; off >>= 1) {
    ssim_acc += __shfl_down(ssim_acc, off);
    cs_acc += __shfl_down(cs_acc, off);
  }
  if (lane == 0) {
    partials[2 * gwid] = ssim_acc;
    partials[2 * gwid + 1] = cs_acc;
  }
}

// ---------------------------------------------------------------------------
__global__ __launch_bounds__(256) void final_kernel(
    const float* __restrict__ ws, float* __restrict__ out)
{
  __shared__ double sred[2][4];
  __shared__ double fin[11];  // ssim[5], cs[5], mse
  const int tid = threadIdx.x;
  const int offs[5] = {P_L0, P_L1, P_L2, P_L3, P_L4};
  const int cnts[5] = {3072, 768, 192, 96, 48};

  for (int l = 0; l < 5; ++l) {
    double s0 = 0.0, s1 = 0.0;
    for (int i = tid; i < cnts[l]; i += 256) {
      s0 += (double)ws[offs[l] + 2 * i];
      s1 += (double)ws[offs[l] + 2 * i + 1];
    }
#pragma unroll
    for (int off = 32; off; off >>= 1) {
      s0 += __shfl_down(s0, off);
      s1 += __shfl_down(s1, off);
    }
    if ((tid & 63) == 0) { sred[0][tid >> 6] = s0; sred[1][tid >> 6] = s1; }
    __syncthreads();
    if (tid == 0) {
      double aa = 0.0, bb = 0.0;
      for (int i = 0; i < 4; ++i) { aa += sred[0][i]; bb += sred[1][i]; }
      fin[l] = aa;
      fin[5 + l] = bb;
    }
    __syncthreads();
  }

  {
    double s0 = 0.0;
    for (int i = tid; i < 3072; i += 256) s0 += (double)ws[P_MSE + i];
#pragma unroll
    for (int off = 32; off; off >>= 1) s0 += __shfl_down(s0, off);
    if ((tid & 63) == 0) sred[0][tid >> 6] = s0;
    __syncthreads();
    if (tid == 0) {
      double aa = 0.0;
      for (int i = 0; i < 4; ++i) aa += sred[0][i];
      fin[10] = aa;
    }
    __syncthreads();
  }

  if (tid == 0) {
    const double wts[5] = {0.0448, 0.2856, 0.3001, 0.2363, 0.1333};
    const double dims[5] = {502.0, 246.0, 118.0, 54.0, 22.0};
    double mssim[5], mcs[5];
    for (int l = 0; l < 5; ++l) {
      double n = 48.0 * dims[l] * dims[l];
      mssim[l] = fin[l] / n;
      mcs[l] = fin[5 + l] / n;
    }
    // literal pytorch_msssim translation: prod(pow1[:-1] * pow2[-1])
    double p2last = pow(mssim[4], wts[4]);
    double prod = 1.0;
    for (int i = 0; i < 4; ++i) prod *= pow(mcs[i], wts[i]) * p2last;
    double msssim = prod;
    double mse = fin[10] / 12582912.0;
    out[0] = (float)(mse - msssim + 1.0);
    out[1] = (float)msssim;
  }
}

// ---------------------------------------------------------------------------
extern "C" void kernel_launch(void* const* d_in, const int* in_sizes, int n_in,
                              void* d_out, int out_size, void* d_ws, size_t ws_size,
                              hipStream_t stream)
{
  const float* rec = (const float*)d_in[0];   // reconst
  const float* orig = (const float*)d_in[1];  // original
  float* ws = (float*)d_ws;
  float* out = (float*)d_out;

  GaussW gw;
  {
    double g[11], s = 0.0;
    for (int i = 0; i < 11; ++i) {
      double x = (double)i - 5.0;
      g[i] = exp(-(x * x) / 4.5);
      s += g[i];
    }
    for (int i = 0; i < 11; ++i) gw.g[i] = (float)(g[i] / s);
  }

  // pyramid pointers
  float* A1 = ws + 0;
  float* A2 = ws + 3145728;
  float* A3 = ws + 3932160;
  float* A4 = ws + 4128768;
  float* B1 = ws + PYR2_OFF;
  float* B2 = ws + PYR2_OFF + 3145728;
  float* B3 = ws + PYR2_OFF + 3932160;
  float* B4 = ws + PYR2_OFF + 4128768;

  // L0..L2: packed 2-px/lane streaming. waves = 48*RS*CS, blocks = waves/4
  ssim_pk<9, 1, 1><<<dim3(768), 256, 0, stream>>>(
      orig, rec, gw, ws + P_L0, ws + P_MSE, A1, B1);   // 16 bands x 4 strips
  ssim_pk<8, 0, 1><<<dim3(192), 256, 0, stream>>>(
      A1, B1, gw, ws + P_L1, nullptr, A2, B2);         // 8 x 2
  ssim_pk<7, 0, 1><<<dim3(48), 256, 0, stream>>>(
      A2, B2, gw, ws + P_L2, nullptr, A3, B3);         // 4 x 1
  // L3/L4: scalar LDS-ring kernel
  ssim_small<6, 1><<<dim3(24), 256, 0, stream>>>(
      A3, B3, gw, ws + P_L3, A4, B4);                  // 2 x 1
  ssim_small<5, 0><<<dim3(12), 256, 0, stream>>>(
      A4, B4, gw, ws + P_L4, nullptr, nullptr);        // 1 x 1

  final_kernel<<<dim3(1), dim3(256), 0, stream>>>(ws, out);
}